// Round 1
// baseline (450.623 us; speedup 1.0000x reference)
//
#include <hip/hip_runtime.h>
#include <math.h>

#define DD 192
#define HH 192
#define WW 384
#define WV 575           // W + D - 1
#define PIX 32           // pixels per block
#define NCHUNK 8         // d-chunks per block
#define DPC 24           // d values per chunk (8*24 = 192)

__global__ __launch_bounds__(256, 4) void vr_kernel(const float* __restrict__ v,
                                                    float* __restrict__ out) {
    const int t = threadIdx.x;
    const int wl = t & (PIX - 1);      // pixel within tile
    const int chunk = t >> 5;          // d-chunk 0..7
    const int tile = blockIdx.x;       // 0..2303
    const int h = tile / (WW / PIX);
    const int w0 = (tile % (WW / PIX)) * PIX;
    const int w = w0 + wl;

    const size_t dstride = (size_t)HH * WV;       // 110400 floats per d-plane
    const size_t cstride = (size_t)DD * dstride;  // channel stride
    const float* base = v + (size_t)h * WV + (size_t)w;

    // online-softmax state: pass1 (aligned) and pass2 (diagonal)
    float m1 = -INFINITY, l1 = 0.f, a1 = 0.f, c10 = 0.f, c11 = 0.f, c12 = 0.f;
    float m2 = -INFINITY, l2 = 0.f, a2 = 0.f, c20 = 0.f, c21 = 0.f, c22 = 0.f;

    const int d0 = chunk * DPC;
    const float* p = base + (size_t)d0 * dstride;
    #pragma unroll 4
    for (int i = 0; i < DPC; ++i) {
        const int d = d0 + i;
        const int sh = (DD - 1) - d;           // diagonal shift, also the disp value
        // 8 coalesced scalar loads (lane = w -> contiguous addresses)
        float b1  = p[0];
        float b2  = p[sh];
        float x10 = p[cstride];
        float x20 = p[cstride + sh];
        float x11 = p[2 * cstride];
        float x21 = p[2 * cstride + sh];
        float x12 = p[3 * cstride];
        float x22 = p[3 * cstride + sh];
        const float dv = (float)sh;

        // pass 1 online softmax update
        float nm = fmaxf(m1, b1);
        float s  = __expf(m1 - nm);
        float pr = __expf(b1 - nm);
        l1  = l1  * s + pr;
        a1  = a1  * s + pr * dv;
        c10 = c10 * s + pr * x10;
        c11 = c11 * s + pr * x11;
        c12 = c12 * s + pr * x12;
        m1 = nm;

        // pass 2 online softmax update
        nm = fmaxf(m2, b2);
        s  = __expf(m2 - nm);
        pr = __expf(b2 - nm);
        l2  = l2  * s + pr;
        a2  = a2  * s + pr * dv;
        c20 = c20 * s + pr * x20;
        c21 = c21 * s + pr * x21;
        c22 = c22 * s + pr * x22;
        m2 = nm;

        p += dstride;
    }

    // merge the 8 partial softmax states per pixel via LDS
    __shared__ float sm[NCHUNK][PIX][12];
    float* sp = sm[chunk][wl];
    sp[0] = m1; sp[1] = l1; sp[2]  = a1; sp[3]  = c10; sp[4]  = c11; sp[5]  = c12;
    sp[6] = m2; sp[7] = l2; sp[8]  = a2; sp[9]  = c20; sp[10] = c21; sp[11] = c22;
    __syncthreads();

    if (t < 2 * PIX) {
        const int pix  = t & (PIX - 1);
        const int pass = t >> 5;        // 0 = aligned, 1 = diagonal
        const int off  = pass * 6;
        float M = -INFINITY, L = 0.f, A = 0.f, C0 = 0.f, C1 = 0.f, C2 = 0.f;
        #pragma unroll
        for (int ch = 0; ch < NCHUNK; ++ch) {
            const float* q = sm[ch][pix] + off;
            float mm = q[0];
            float nm = fmaxf(M, mm);
            float s0 = __expf(M - nm);
            float s1 = __expf(mm - nm);
            L  = L  * s0 + q[1] * s1;
            A  = A  * s0 + q[2] * s1;
            C0 = C0 * s0 + q[3] * s1;
            C1 = C1 * s0 + q[4] * s1;
            C2 = C2 * s0 + q[5] * s1;
            M = nm;
        }
        const float inv = 1.0f / L;
        const int HW = HH * WW;
        const int o = h * WW + w0 + pix;
        // outputs flat-concatenated: color_1 (3HW), color_2 (3HW), disp_1 (HW), disp_2 (HW)
        out[(pass * 3 + 0) * HW + o] = C0 * inv;
        out[(pass * 3 + 1) * HW + o] = C1 * inv;
        out[(pass * 3 + 2) * HW + o] = C2 * inv;
        out[(6 + pass) * HW + o]     = A * inv;
    }
}

extern "C" void kernel_launch(void* const* d_in, const int* in_sizes, int n_in,
                              void* d_out, int out_size, void* d_ws, size_t ws_size,
                              hipStream_t stream) {
    const float* v = (const float*)d_in[0];
    float* out = (float*)d_out;
    const int grid = (HH * WW / PIX);   // 2304 blocks, 256 threads
    vr_kernel<<<grid, 256, 0, stream>>>(v, out);
}